// Round 12
// baseline (139.025 us; speedup 1.0000x reference)
//
#include <hip/hip_runtime.h>
#include <hip/hip_bf16.h>
#include <cstddef>

// Problem constants (reference: B=128, IN=1024, H=1024, TAU=1.0)
#define B_DIM  128
#define IN_DIM 1024
#define H_DIM  1024

constexpr float kDecay   = 1.0f - 0.01f;    // 1 - FAST_WEIGHT_DECAY
constexpr float kLrOverB = 0.01f / 128.0f;  // FAST_WEIGHT_LR / B

// Native clang vector type: __builtin_nontemporal_load needs this.
typedef float f32x4 __attribute__((ext_vector_type(4)));

// ---------------------------------------------------------------------------
// Kernel 0: ic[b][o] = x_t[b,:] . W_ih[o,:] + b_ih[o]     (268 MFLOP GEMM)
// ---------------------------------------------------------------------------
__global__ __launch_bounds__(256) void input_gemm(
    const float* __restrict__ x_t,   // (B, IN)
    const float* __restrict__ W_ih,  // (H, IN)
    const float* __restrict__ b_ih,  // (H,)
    float* __restrict__ ic)          // (B, H)  [workspace]
{
    const int o0 = blockIdx.x * 64;
    const int b0 = blockIdx.y * 16;
    const int t  = threadIdx.x;

    __shared__ float Wt[64][68];   // [k][o]
    __shared__ float xs[64][17];   // [k][b]

    const int tx = t & 15;         // o group: 4 outputs at o0 + 4*tx
    const int ty = t >> 4;         // b: b0 + ty

    float acc[4] = {0.f, 0.f, 0.f, 0.f};

    for (int kc = 0; kc < IN_DIM / 64; ++kc) {
        const int k0 = kc * 64;

#pragma unroll
        for (int ii = 0; ii < 4; ++ii) {
            const int i  = t + 256 * ii;
            const int r  = i >> 4;
            const int c4 = (i & 15) * 4;
            const float4 wv = *reinterpret_cast<const float4*>(
                &W_ih[(size_t)(o0 + r) * IN_DIM + k0 + c4]);
            Wt[c4 + 0][r] = wv.x; Wt[c4 + 1][r] = wv.y;
            Wt[c4 + 2][r] = wv.z; Wt[c4 + 3][r] = wv.w;
        }
        {
            const int br = t >> 4;
            const int c4 = (t & 15) * 4;
            const float4 xv = *reinterpret_cast<const float4*>(
                &x_t[(size_t)(b0 + br) * IN_DIM + k0 + c4]);
            xs[c4 + 0][br] = xv.x; xs[c4 + 1][br] = xv.y;
            xs[c4 + 2][br] = xv.z; xs[c4 + 3][br] = xv.w;
        }
        __syncthreads();

#pragma unroll 8
        for (int k = 0; k < 64; ++k) {
            const float  xb = xs[k][ty];
            const float4 wv = *reinterpret_cast<const float4*>(&Wt[k][4 * tx]);
            acc[0] = fmaf(wv.x, xb, acc[0]);
            acc[1] = fmaf(wv.y, xb, acc[1]);
            acc[2] = fmaf(wv.z, xb, acc[2]);
            acc[3] = fmaf(wv.w, xb, acc[3]);
        }
        __syncthreads();
    }

    const int o = o0 + 4 * tx;
    const int b = b0 + ty;
    float4 r;
    r.x = acc[0] + b_ih[o + 0];
    r.y = acc[1] + b_ih[o + 1];
    r.z = acc[2] + b_ih[o + 2];
    r.w = acc[3] + b_ih[o + 3];
    *reinterpret_cast<float4*>(&ic[(size_t)b * H_DIM + o]) = r;
}

// ---------------------------------------------------------------------------
// Kernel A (v12): gumbel-softmax exchange + tanh. Single-round persistent
//   (R11 winner) + 3-deep register ring: while tile g is consumed, tiles
//   g+1 and g+2 are in flight (~8 KB/wave avg, 128 KB/CU at 16 waves/CU).
//   Ring slot = g % 3, compile-time after full unroll; refill of tile g+3
//   crosses b-batch boundaries so the stream never drains, including through
//   the shuffle-reduction phase. pn prefetch dropped (frees 16 VGPR): pc is
//   loaded at batch start and its L2 latency hides under the first tile's
//   transcendental chain (pc is only needed by the trailing fmas).
//   grid = (H/8, B/16) = 1024 blocks = 4/CU, one dispatch round; x = o-chunk
//   so the 8 blocks sharing an o-chunk land on one XCD (weights L2-shared).
// ---------------------------------------------------------------------------
__global__ __launch_bounds__(256, 4) void fused_rows(
    const float* __restrict__ h_prev,  // (B, H)
    const float* __restrict__ W_f,     // (H, H)
    const float* __restrict__ W_v,     // (H, H)
    const float* __restrict__ gu,      // (B, H, H)
    const float* __restrict__ ic,      // (B, H)  [workspace, bias included]
    float* __restrict__ h_next)        // (B, H)  [= d_out region 0]
{
    const int o0 = blockIdx.x * 8;
    const int b0 = blockIdx.y * 16;
    const int t  = threadIdx.x;
    const int w  = t >> 6, lane = t & 63;

    __shared__ __align__(16) float e_s[8 * H_DIM];  // 32 KB exp(logits) rows

    // Stage exp(W_f + W_v) for rows o0..o0+7 (fused exp).
    {
        const float4* f4 = reinterpret_cast<const float4*>(W_f) + (size_t)o0 * 256;
        const float4* v4 = reinterpret_cast<const float4*>(W_v) + (size_t)o0 * 256;
        float4*       dst = reinterpret_cast<float4*>(e_s);
#pragma unroll
        for (int ii = 0; ii < 8; ++ii) {
            const float4 a = f4[t + 256 * ii];
            const float4 b = v4[t + 256 * ii];
            float4 ee;
            ee.x = __expf(a.x + b.x); ee.y = __expf(a.y + b.y);
            ee.z = __expf(a.z + b.z); ee.w = __expf(a.w + b.w);
            dst[t + 256 * ii] = ee;
        }
    }
    __syncthreads();

    const float4* e4 = reinterpret_cast<const float4*>(e_s);
    const int bA = b0 + w;   // wave's first b; sequence: bA + 4k, k = 0..3

    // Per-batch gumbel row bases (f32x4 units), all indices compile-time.
    const f32x4* gbase[4];
#pragma unroll
    for (int kk = 0; kk < 4; ++kk)
        gbase[kk] = reinterpret_cast<const f32x4*>(gu)
                  + ((size_t)(bA + 4 * kk) * H_DIM + o0) * 256;

    f32x4 ug[3][4];   // 3-deep register ring; tile g lives in slot g % 3

    // Prologue: tiles g = 0,1,2 (nontemporal one-touch stream).
#pragma unroll
    for (int g = 0; g < 3; ++g)
#pragma unroll
        for (int j = 0; j < 4; ++j)
            ug[g][j] = __builtin_nontemporal_load(gbase[0] + g * 256 + lane + 64 * j);

    float4 pc[4];

#pragma unroll
    for (int k = 0; k < 4; ++k) {
        const int b = bA + 4 * k;

        // h_prev[b] -> 16 VGPRs; latency hides under tile 8k's trans chain.
        {
            const float4* hp4 = reinterpret_cast<const float4*>(
                h_prev + (size_t)b * H_DIM);
#pragma unroll
            for (int j = 0; j < 4; ++j) pc[j] = hp4[lane + 64 * j];
        }

        float s[8], d[8];

#pragma unroll
        for (int oi = 0; oi < 8; ++oi) {
            const int g    = 8 * k + oi;   // global tile index 0..31
            const int slot = g % 3;        // compile-time after unroll

            float sum = 0.f, dot = 0.f;
#pragma unroll
            for (int j = 0; j < 4; ++j) {
                const f32x4  uu = ug[slot][j];
                const float4 ee = e4[oi * 256 + lane + 64 * j];
                const float4 pp = pc[j];
                const float q0 = __fdividef(ee.x, -__log2f(fmaxf(uu.x, 1e-9f)));
                const float q1 = __fdividef(ee.y, -__log2f(fmaxf(uu.y, 1e-9f)));
                const float q2 = __fdividef(ee.z, -__log2f(fmaxf(uu.z, 1e-9f)));
                const float q3 = __fdividef(ee.w, -__log2f(fmaxf(uu.w, 1e-9f)));
                sum += (q0 + q1) + (q2 + q3);
                dot = fmaf(q0, pp.x, dot);
                dot = fmaf(q1, pp.y, dot);
                dot = fmaf(q2, pp.z, dot);
                dot = fmaf(q3, pp.w, dot);
            }
            s[oi] = sum;
            d[oi] = dot;

            // Refill this slot with tile g+3 (crosses batch boundaries).
            const int gn = g + 3;
            if (gn < 32) {
                const int kk = gn >> 3;    // compile-time
                const int on = gn & 7;
                const f32x4* gsrc = gbase[kk] + (size_t)on * 256;
#pragma unroll
                for (int j = 0; j < 4; ++j)
                    ug[slot][j] = __builtin_nontemporal_load(gsrc + lane + 64 * j);
            }
        }

        // 16 independent xor-reduction chains for this b (deferred, high ILP).
#pragma unroll
        for (int off = 32; off > 0; off >>= 1) {
#pragma unroll
            for (int r = 0; r < 8; ++r) {
                s[r] += __shfl_xor(s[r], off, 64);
                d[r] += __shfl_xor(d[r], off, 64);
            }
        }

        if (lane == 0) {
            const size_t base = (size_t)b * H_DIM + o0;
            const float4 i0 = *reinterpret_cast<const float4*>(ic + base);
            const float4 i1 = *reinterpret_cast<const float4*>(ic + base + 4);
            float4 r0, r1;
            r0.x = tanhf(i0.x + __fdividef(d[0], s[0]));
            r0.y = tanhf(i0.y + __fdividef(d[1], s[1]));
            r0.z = tanhf(i0.z + __fdividef(d[2], s[2]));
            r0.w = tanhf(i0.w + __fdividef(d[3], s[3]));
            r1.x = tanhf(i1.x + __fdividef(d[4], s[4]));
            r1.y = tanhf(i1.y + __fdividef(d[5], s[5]));
            r1.z = tanhf(i1.z + __fdividef(d[6], s[6]));
            r1.w = tanhf(i1.w + __fdividef(d[7], s[7]));
            *reinterpret_cast<float4*>(h_next + base)     = r0;
            *reinterpret_cast<float4*>(h_next + base + 4) = r1;
        }
    }
}

// ---------------------------------------------------------------------------
// Kernel B: W_out = 0.99 * W_v + (0.01/B) * (h_next^T @ h_prev)
// ---------------------------------------------------------------------------
__global__ __launch_bounds__(256) void hebbian_update(
    const float* __restrict__ h_next,  // (B, H)
    const float* __restrict__ h_prev,  // (B, H)
    const float* __restrict__ W_v,     // (H, H)
    float* __restrict__ W_out)         // (H, H)  [= d_out region 1]
{
    const int h0 = blockIdx.x * 64;
    const int o0 = blockIdx.y * 64;
    const int t  = threadIdx.x;

    __shared__ __align__(16) float hn_s[B_DIM][64];  // 32 KB
    __shared__ __align__(16) float hp_s[B_DIM][64];  // 32 KB

#pragma unroll
    for (int i = 0; i < 32; ++i) {
        const int e  = t + 256 * i;
        const int bb = e >> 6;
        const int cc = e & 63;
        hn_s[bb][cc] = h_next[(size_t)bb * H_DIM + o0 + cc];
        hp_s[bb][cc] = h_prev[(size_t)bb * H_DIM + h0 + cc];
    }
    __syncthreads();

    const int tx = t & 15;   // h group
    const int ty = t >> 4;   // o group

    float acc[4][4] = {{0.f}};

#pragma unroll 8
    for (int b = 0; b < B_DIM; ++b) {
        const float4 av = reinterpret_cast<const float4*>(hn_s[b])[ty];
        const float4 bv = reinterpret_cast<const float4*>(hp_s[b])[tx];
        const float aa[4] = {av.x, av.y, av.z, av.w};
        const float bb[4] = {bv.x, bv.y, bv.z, bv.w};
#pragma unroll
        for (int a = 0; a < 4; ++a)
#pragma unroll
            for (int c = 0; c < 4; ++c)
                acc[a][c] = fmaf(aa[a], bb[c], acc[a][c]);
    }

#pragma unroll
    for (int a = 0; a < 4; ++a) {
        const int o = o0 + 4 * ty + a;
        const size_t base = (size_t)o * H_DIM + h0 + 4 * tx;
        const float4 wv = *reinterpret_cast<const float4*>(W_v + base);
        float4 r;
        r.x = wv.x * kDecay + acc[a][0] * kLrOverB;
        r.y = wv.y * kDecay + acc[a][1] * kLrOverB;
        r.z = wv.z * kDecay + acc[a][2] * kLrOverB;
        r.w = wv.w * kDecay + acc[a][3] * kLrOverB;
        *reinterpret_cast<float4*>(W_out + base) = r;
    }
}

// ---------------------------------------------------------------------------
extern "C" void kernel_launch(void* const* d_in, const int* in_sizes, int n_in,
                              void* d_out, int out_size, void* d_ws, size_t ws_size,
                              hipStream_t stream)
{
    const float* x_t    = (const float*)d_in[0];
    const float* h_prev = (const float*)d_in[1];
    const float* W_ih   = (const float*)d_in[2];
    const float* b_ih   = (const float*)d_in[3];
    const float* W_f    = (const float*)d_in[4];
    const float* W_v    = (const float*)d_in[5];
    const float* gu     = (const float*)d_in[6];

    float* out    = (float*)d_out;
    float* h_next = out;                               // (B, H)
    float* W_out  = out + (size_t)B_DIM * H_DIM;       // (H, H)

    float* ic = (float*)d_ws;                          // (B, H) scratch

    input_gemm<<<dim3(H_DIM / 64, B_DIM / 16), 256, 0, stream>>>(
        x_t, W_ih, b_ih, ic);

    fused_rows<<<dim3(H_DIM / 8, B_DIM / 16), 256, 0, stream>>>(
        h_prev, W_f, W_v, gu, ic, h_next);

    hebbian_update<<<dim3(H_DIM / 64, H_DIM / 64), 256, 0, stream>>>(
        h_next, h_prev, W_v, W_out);
}